// Round 1
// baseline (466.770 us; speedup 1.0000x reference)
//
#include <hip/hip_runtime.h>
#include <hip/hip_bf16.h>

typedef __attribute__((ext_vector_type(4))) float f32x4;
typedef __attribute__((ext_vector_type(8))) short bf16x8;
typedef __attribute__((ext_vector_type(4))) short bf16x4v;

#define M_DIM 8192
#define N_DIM 4096
#define K_DIM 4096
#define BM 128
#define BN 128
#define BK 32
#define NKTILES (K_DIM / BK)   // 128
#define LDSS 40                // bf16 elems per LDS row (80 B: 20-bank rotation, 16B-aligned)

__global__ __launch_bounds__(256) void sparse_gemm_bias_relu(
    const float* __restrict__ X,
    const float* __restrict__ W,
    const float* __restrict__ bias,
    float* __restrict__ Y) {
  __shared__ short As[BM * LDSS];
  __shared__ short Bs[BN * LDSS];

  const int tid  = threadIdx.x;
  const int lane = tid & 63;
  const int wave = tid >> 6;          // 0..3
  const int wm = (wave >> 1) * 64;    // wave's row offset inside tile
  const int wn = (wave & 1) * 64;     // wave's col offset inside tile

  const int bn = blockIdx.x;          // 0..31  (N tiles)
  const int bm = blockIdx.y;          // 0..63  (M tiles)
  const long rowA0 = (long)bm * BM;
  const long rowB0 = (long)bn * BN;

  // Staging map: thread t loads one fp32x4; 8 threads cover one 32-fp32 row,
  // 256 threads cover 32 rows per issue, 4 issues cover 128 rows.
  const int srow = tid >> 3;          // 0..31
  const int scol = (tid & 7) * 4;     // 0,4,...,28

  const float* Aptr = X + (rowA0 + srow) * (long)K_DIM + scol;
  const float* Bptr = W + (rowB0 + srow) * (long)K_DIM + scol;

  f32x4 ra[4], rb[4];
#pragma unroll
  for (int i = 0; i < 4; ++i) {
    ra[i] = *(const f32x4*)(Aptr + (long)i * 32 * K_DIM);
    rb[i] = *(const f32x4*)(Bptr + (long)i * 32 * K_DIM);
  }

  f32x4 acc[4][4];
#pragma unroll
  for (int i = 0; i < 4; ++i)
#pragma unroll
    for (int j = 0; j < 4; ++j) acc[i][j] = (f32x4)0.0f;

  for (int kt = 0; kt < NKTILES; ++kt) {
    __syncthreads();                  // previous tile's compute done; LDS free
    // Convert staged fp32 regs -> bf16, write to LDS.
#pragma unroll
    for (int i = 0; i < 4; ++i) {
      bf16x4v pa, pb;
#pragma unroll
      for (int j = 0; j < 4; ++j) {
        pa[j] = (short)__bfloat16_as_ushort(__float2bfloat16(ra[i][j]));
        pb[j] = (short)__bfloat16_as_ushort(__float2bfloat16(rb[i][j]));
      }
      *(bf16x4v*)&As[(i * 32 + srow) * LDSS + scol] = pa;
      *(bf16x4v*)&Bs[(i * 32 + srow) * LDSS + scol] = pb;
    }
    // Issue next k-tile's global loads now; they complete under the MFMA phase.
    if (kt + 1 < NKTILES) {
      const float* An = Aptr + (kt + 1) * BK;
      const float* Bn = Bptr + (kt + 1) * BK;
#pragma unroll
      for (int i = 0; i < 4; ++i) {
        ra[i] = *(const f32x4*)(An + (long)i * 32 * K_DIM);
        rb[i] = *(const f32x4*)(Bn + (long)i * 32 * K_DIM);
      }
    }
    __syncthreads();                  // LDS tile ready
    // Fragment loads: lane l -> row (l&15), k-chunk (l>>4)*8 (one ds_read_b128).
    bf16x8 af[4], bfr[4];
#pragma unroll
    for (int i = 0; i < 4; ++i) {
      af[i]  = *(const bf16x8*)&As[(wm + i * 16 + (lane & 15)) * LDSS + (lane >> 4) * 8];
      bfr[i] = *(const bf16x8*)&Bs[(wn + i * 16 + (lane & 15)) * LDSS + (lane >> 4) * 8];
    }
#pragma unroll
    for (int i = 0; i < 4; ++i)
#pragma unroll
      for (int j = 0; j < 4; ++j)
        acc[i][j] = __builtin_amdgcn_mfma_f32_16x16x32_bf16(af[i], bfr[j], acc[i][j], 0, 0, 0);
  }

  // Epilogue: C/D layout col = lane&15 (n), row = (lane>>4)*4 + reg (m).
  const int r0 = (lane >> 4) * 4;
  const int c0 = lane & 15;
#pragma unroll
  for (int j = 0; j < 4; ++j) {
    const long gc = rowB0 + wn + j * 16 + c0;
    const float bv = bias[gc];
#pragma unroll
    for (int i = 0; i < 4; ++i) {
      const long gr0 = rowA0 + wm + i * 16 + r0;
#pragma unroll
      for (int r = 0; r < 4; ++r) {
        float v = acc[i][j][r] + bv;
        v = v > 0.0f ? v : 0.0f;
        Y[(gr0 + r) * (long)N_DIM + gc] = v;
      }
    }
  }
}

extern "C" void kernel_launch(void* const* d_in, const int* in_sizes, int n_in,
                              void* d_out, int out_size, void* d_ws, size_t ws_size,
                              hipStream_t stream) {
  const float* x = (const float*)d_in[0];
  const float* w = (const float*)d_in[1];
  const float* b = (const float*)d_in[2];
  float* y = (float*)d_out;
  dim3 grid(N_DIM / BN, M_DIM / BM);
  sparse_gemm_bias_relu<<<grid, dim3(256), 0, stream>>>(x, w, b, y);
}

// Round 2
// 291.775 us; speedup vs baseline: 1.5998x; 1.5998x over previous
//
#include <hip/hip_runtime.h>
#include <hip/hip_bf16.h>

typedef __attribute__((ext_vector_type(4))) float f32x4;
typedef __attribute__((ext_vector_type(8))) short bf16x8;
typedef __attribute__((ext_vector_type(4))) short bf16x4v;

#define M_DIM 8192
#define N_DIM 4096
#define K_DIM 4096
#define NX (M_DIM * K_DIM)   /* 33554432 x elems */
#define NW (N_DIM * K_DIM)   /* 16777216 w elems */

#define BM 256
#define BN 256
#define BK 32
#define NKT (K_DIM / BK)     /* 128 */
#define THREADS 512

#define GLOAD_LDS16(g, l)                                                        \
  __builtin_amdgcn_global_load_lds(                                              \
      (const __attribute__((address_space(1))) void*)(g),                        \
      (__attribute__((address_space(3))) void*)(l), 16, 0, 0)

// ---------------------------------------------------------------------------
// Pass 1: fp32 -> bf16 conversion of x and W into workspace.
// ---------------------------------------------------------------------------
__global__ __launch_bounds__(256) void convert_bf16(const float* __restrict__ x,
                                                    const float* __restrict__ w,
                                                    short* __restrict__ ws) {
  const long stride = (long)gridDim.x * blockDim.x;
  const long total8 = ((long)NX + NW) / 8;
  for (long i = blockIdx.x * (long)blockDim.x + threadIdx.x; i < total8; i += stride) {
    const long base = i * 8;
    const float* src;
    short* dst;
    if (base < NX) {
      src = x + base;
      dst = ws + base;
    } else {
      src = w + (base - NX);
      dst = ws + base;  // w region starts at ws + NX, base already includes NX
    }
    f32x4 a = *(const f32x4*)src;
    f32x4 b = *(const f32x4*)(src + 4);
    bf16x8 o;
    o[0] = (short)__bfloat16_as_ushort(__float2bfloat16(a[0]));
    o[1] = (short)__bfloat16_as_ushort(__float2bfloat16(a[1]));
    o[2] = (short)__bfloat16_as_ushort(__float2bfloat16(a[2]));
    o[3] = (short)__bfloat16_as_ushort(__float2bfloat16(a[3]));
    o[4] = (short)__bfloat16_as_ushort(__float2bfloat16(b[0]));
    o[5] = (short)__bfloat16_as_ushort(__float2bfloat16(b[1]));
    o[6] = (short)__bfloat16_as_ushort(__float2bfloat16(b[2]));
    o[7] = (short)__bfloat16_as_ushort(__float2bfloat16(b[3]));
    *(bf16x8*)dst = o;
  }
}

// ---------------------------------------------------------------------------
// Pass 2: 256x256 bf16 GEMM, BK=32, 8 waves (2M x 4N), 3-deep LDS ring,
// global_load_lds(16B) staging, counted vmcnt(4), XOR slot swizzle, setprio.
// Y = relu(X @ W^T + b)
// ---------------------------------------------------------------------------
__global__ __launch_bounds__(THREADS, 2) void gemm256_bf16(
    const short* __restrict__ Abf,   /* [M][K] bf16 */
    const short* __restrict__ Bbf,   /* [N][K] bf16 */
    const float* __restrict__ bias,
    float* __restrict__ Y) {
  // buffer b: A at b*16384 shorts (16KB), B at b*16384+8192
  __shared__ short lds[3 * 16384];

  const int tid  = threadIdx.x;
  const int lane = tid & 63;
  const int wave = tid >> 6;       // 0..7
  const int wm   = wave >> 2;      // 0..1  (M half)
  const int wn   = wave & 3;       // 0..3  (N quarter)

  const long rowA0 = (long)blockIdx.y * BM;
  const long rowB0 = (long)blockIdx.x * BN;

  // Staging geometry: one GLOAD issue = 512 thr x 16B = 8KB = 128 rows x 64B.
  // Within issue: row = is*128 + wave*16 + lane/4, phys slot = lane%3... lane&3.
  const int s_row_lo = wave * 16 + (lane >> 2);  // 0..127
  const int s_phys   = lane & 3;

  f32x4 acc[8][4];
#pragma unroll
  for (int i = 0; i < 8; ++i)
#pragma unroll
    for (int j = 0; j < 4; ++j) acc[i][j] = (f32x4)0.0f;

  // ---- staging: issue 4 global_load_lds for K-tile kt into buffer buf ----
  auto stage = [&](int buf, int kt) {
#pragma unroll
    for (int is = 0; is < 2; ++is) {
      const int row     = is * 128 + s_row_lo;        // 0..255 tile row
      const int logical = s_phys ^ ((row >> 1) & 3);  // inverse-swizzled source slot
      const long gcol   = (long)kt * BK + logical * 8;
      // A
      GLOAD_LDS16(Abf + (rowA0 + row) * (long)K_DIM + gcol,
                  &lds[buf * 16384 + is * 4096 + wave * 512]);
      // B
      GLOAD_LDS16(Bbf + (rowB0 + row) * (long)K_DIM + gcol,
                  &lds[buf * 16384 + 8192 + is * 4096 + wave * 512]);
    }
  };

  // fragment read geometry: lane -> row (lane&15), logical k-slot (lane>>4)
  const int frow = lane & 15;
  const int fsl  = lane >> 4;  // 0..3 (8 bf16 = 16B per slot)

  // ---- prologue: prefetch tiles 0 and 1 ----
  stage(0, 0);
  stage(1, 1);
  asm volatile("s_waitcnt vmcnt(4)" ::: "memory");  // tile 0 complete; tile 1 in flight
  __builtin_amdgcn_s_barrier();
  __builtin_amdgcn_sched_barrier(0);

  for (int kt = 0; kt < NKT; ++kt) {
    const int cur = kt % 3;
    // issue tile kt+2 into the ring slot freed by tile kt-1
    if (kt + 2 < NKT) stage((kt + 2) % 3, kt + 2);

    const short* As = &lds[cur * 16384];
    const short* Bs = &lds[cur * 16384 + 8192];
    bf16x8 af[8], bfr[4];
#pragma unroll
    for (int i = 0; i < 8; ++i) {
      const int row = wm * 128 + i * 16 + frow;
      const int ph  = fsl ^ ((row >> 1) & 3);
      af[i] = *(const bf16x8*)&As[row * 32 + ph * 8];
    }
#pragma unroll
    for (int j = 0; j < 4; ++j) {
      const int row = wn * 64 + j * 16 + frow;
      const int ph  = fsl ^ ((row >> 1) & 3);
      bfr[j] = *(const bf16x8*)&Bs[row * 32 + ph * 8];
    }

    __builtin_amdgcn_s_setprio(1);
#pragma unroll
    for (int i = 0; i < 8; ++i)
#pragma unroll
      for (int j = 0; j < 4; ++j)
        acc[i][j] = __builtin_amdgcn_mfma_f32_16x16x32_bf16(af[i], bfr[j], acc[i][j], 0, 0, 0);
    __builtin_amdgcn_s_setprio(0);

    if (kt + 1 < NKT) {
      // tile kt+1 must be resident before next iteration reads it; keep the
      // newest 4 loads (tile kt+2) in flight across the barrier.
      if (kt + 2 < NKT)
        asm volatile("s_waitcnt vmcnt(4)" ::: "memory");
      else
        asm volatile("s_waitcnt vmcnt(0)" ::: "memory");
      __builtin_amdgcn_s_barrier();
      __builtin_amdgcn_sched_barrier(0);
    }
  }

  // ---- epilogue: bias + relu, fp32 stores ----
  const int c0 = lane & 15;
  const int r0 = (lane >> 4) * 4;
#pragma unroll
  for (int j = 0; j < 4; ++j) {
    const long gc = rowB0 + wn * 64 + j * 16 + c0;
    const float bv = bias[gc];
#pragma unroll
    for (int i = 0; i < 8; ++i) {
      const long gr0 = rowA0 + wm * 128 + i * 16 + r0;
#pragma unroll
      for (int r = 0; r < 4; ++r) {
        float v = acc[i][j][r] + bv;
        Y[(gr0 + r) * (long)N_DIM + gc] = fmaxf(v, 0.0f);
      }
    }
  }
}

// ---------------------------------------------------------------------------
// Fallback (round-1 kernel, used only if ws is too small): fp32 reg-staged.
// ---------------------------------------------------------------------------
#define FBM 128
#define FBK 32
#define FLDSS 40
__global__ __launch_bounds__(256) void fallback_gemm(
    const float* __restrict__ X, const float* __restrict__ W,
    const float* __restrict__ bias, float* __restrict__ Y) {
  __shared__ short As[FBM * FLDSS];
  __shared__ short Bs[FBM * FLDSS];
  const int tid = threadIdx.x, lane = tid & 63, wave = tid >> 6;
  const int wm = (wave >> 1) * 64, wn = (wave & 1) * 64;
  const long rowA0 = (long)blockIdx.y * FBM, rowB0 = (long)blockIdx.x * FBM;
  const int srow = tid >> 3, scol = (tid & 7) * 4;
  const float* Aptr = X + (rowA0 + srow) * (long)K_DIM + scol;
  const float* Bptr = W + (rowB0 + srow) * (long)K_DIM + scol;
  f32x4 ra[4], rb[4];
#pragma unroll
  for (int i = 0; i < 4; ++i) {
    ra[i] = *(const f32x4*)(Aptr + (long)i * 32 * K_DIM);
    rb[i] = *(const f32x4*)(Bptr + (long)i * 32 * K_DIM);
  }
  f32x4 acc[4][4];
#pragma unroll
  for (int i = 0; i < 4; ++i)
#pragma unroll
    for (int j = 0; j < 4; ++j) acc[i][j] = (f32x4)0.0f;
  for (int kt = 0; kt < K_DIM / FBK; ++kt) {
    __syncthreads();
#pragma unroll
    for (int i = 0; i < 4; ++i) {
      bf16x4v pa, pb;
#pragma unroll
      for (int j = 0; j < 4; ++j) {
        pa[j] = (short)__bfloat16_as_ushort(__float2bfloat16(ra[i][j]));
        pb[j] = (short)__bfloat16_as_ushort(__float2bfloat16(rb[i][j]));
      }
      *(bf16x4v*)&As[(i * 32 + srow) * FLDSS + scol] = pa;
      *(bf16x4v*)&Bs[(i * 32 + srow) * FLDSS + scol] = pb;
    }
    if (kt + 1 < K_DIM / FBK) {
      const float* An = Aptr + (kt + 1) * FBK;
      const float* Bn = Bptr + (kt + 1) * FBK;
#pragma unroll
      for (int i = 0; i < 4; ++i) {
        ra[i] = *(const f32x4*)(An + (long)i * 32 * K_DIM);
        rb[i] = *(const f32x4*)(Bn + (long)i * 32 * K_DIM);
      }
    }
    __syncthreads();
    bf16x8 af[4], bfr[4];
#pragma unroll
    for (int i = 0; i < 4; ++i) {
      af[i]  = *(const bf16x8*)&As[(wm + i * 16 + (lane & 15)) * FLDSS + (lane >> 4) * 8];
      bfr[i] = *(const bf16x8*)&Bs[(wn + i * 16 + (lane & 15)) * FLDSS + (lane >> 4) * 8];
    }
#pragma unroll
    for (int i = 0; i < 4; ++i)
#pragma unroll
      for (int j = 0; j < 4; ++j)
        acc[i][j] = __builtin_amdgcn_mfma_f32_16x16x32_bf16(af[i], bfr[j], acc[i][j], 0, 0, 0);
  }
  const int r0 = (lane >> 4) * 4, c0 = lane & 15;
#pragma unroll
  for (int j = 0; j < 4; ++j) {
    const long gc = rowB0 + wn + j * 16 + c0;
    const float bv = bias[gc];
#pragma unroll
    for (int i = 0; i < 4; ++i) {
      const long gr0 = rowA0 + wm + i * 16 + r0;
#pragma unroll
      for (int r = 0; r < 4; ++r) {
        float v = acc[i][j][r] + bv;
        Y[(gr0 + r) * (long)N_DIM + gc] = fmaxf(v, 0.0f);
      }
    }
  }
}

extern "C" void kernel_launch(void* const* d_in, const int* in_sizes, int n_in,
                              void* d_out, int out_size, void* d_ws, size_t ws_size,
                              hipStream_t stream) {
  const float* x = (const float*)d_in[0];
  const float* w = (const float*)d_in[1];
  const float* b = (const float*)d_in[2];
  float* y = (float*)d_out;

  const size_t need = (size_t)(NX + NW) * sizeof(short);  // ~100.7 MB
  if (ws_size >= need) {
    short* ws = (short*)d_ws;
    convert_bf16<<<2048, 256, 0, stream>>>(x, w, ws);
    dim3 grid(N_DIM / BN, M_DIM / BM);
    gemm256_bf16<<<grid, dim3(THREADS), 0, stream>>>(ws, ws + NX, b, y);
  } else {
    dim3 grid(N_DIM / FBM, M_DIM / FBM);
    fallback_gemm<<<grid, dim3(256), 0, stream>>>(x, w, b, y);
  }
}

// Round 3
// 281.664 us; speedup vs baseline: 1.6572x; 1.0359x over previous
//
#include <hip/hip_runtime.h>
#include <hip/hip_bf16.h>

typedef __attribute__((ext_vector_type(4))) float f32x4;
typedef __attribute__((ext_vector_type(8))) short bf16x8;
typedef __attribute__((ext_vector_type(4))) short bf16x4v;

#define M_DIM 8192
#define N_DIM 4096
#define K_DIM 4096
#define NX (M_DIM * K_DIM)
#define NW (N_DIM * K_DIM)

#define BM 256
#define BN 256
#define BK 64
#define NKT (K_DIM / BK)   /* 64 */
#define THREADS 512

#define GLOAD_LDS16(g, l)                                                        \
  __builtin_amdgcn_global_load_lds(                                              \
      (const __attribute__((address_space(1))) void*)(g),                        \
      (__attribute__((address_space(3))) void*)(l), 16, 0, 0)

// ---------------------------------------------------------------------------
// Pass 1: fp32 -> bf16 conversion of x and W into workspace.
// ---------------------------------------------------------------------------
__global__ __launch_bounds__(256) void convert_bf16(const float* __restrict__ x,
                                                    const float* __restrict__ w,
                                                    short* __restrict__ ws) {
  const long stride = (long)gridDim.x * blockDim.x;
  const long total8 = ((long)NX + NW) / 8;
  for (long i = blockIdx.x * (long)blockDim.x + threadIdx.x; i < total8; i += stride) {
    const long base = i * 8;
    const float* src = (base < NX) ? (x + base) : (w + (base - NX));
    short* dst = ws + base;
    f32x4 a = *(const f32x4*)src;
    f32x4 b = *(const f32x4*)(src + 4);
    bf16x8 o;
    o[0] = (short)__bfloat16_as_ushort(__float2bfloat16(a[0]));
    o[1] = (short)__bfloat16_as_ushort(__float2bfloat16(a[1]));
    o[2] = (short)__bfloat16_as_ushort(__float2bfloat16(a[2]));
    o[3] = (short)__bfloat16_as_ushort(__float2bfloat16(a[3]));
    o[4] = (short)__bfloat16_as_ushort(__float2bfloat16(b[0]));
    o[5] = (short)__bfloat16_as_ushort(__float2bfloat16(b[1]));
    o[6] = (short)__bfloat16_as_ushort(__float2bfloat16(b[2]));
    o[7] = (short)__bfloat16_as_ushort(__float2bfloat16(b[3]));
    *(bf16x8*)dst = o;
  }
}

// ---------------------------------------------------------------------------
// Pass 2: 256x256 bf16 GEMM, BK=64, 8 waves (2M x 4N), double-buffered LDS,
// 4-phase-per-K-tile schedule, counted vmcnt(4), 8-slot XOR swizzle, setprio.
// Y = relu(X @ W^T + b)
//
// LDS map (bytes, per buffer of 64 KiB): half 0 = A rows 0-127, half 1 =
// A rows 128-255, half 2 = B rows 0-127, half 3 = B rows 128-255.
// Within a half: row-major 128 rows x 64 bf16 (128 B), 8 slots of 16 B per
// row, slot swizzle phys = logical ^ (row & 7).
// ---------------------------------------------------------------------------
__global__ __launch_bounds__(THREADS, 2) void gemm256_bf16(
    const short* __restrict__ Abf,   /* [M][K] bf16 */
    const short* __restrict__ Bbf,   /* [N][K] bf16 */
    const float* __restrict__ bias,
    float* __restrict__ Y) {
  __shared__ short lds[2 * 32768];   /* 128 KiB */
  char* const ldsb = (char*)lds;

  const int tid  = threadIdx.x;
  const int lane = tid & 63;
  const int wave = tid >> 6;       // 0..7
  const int wm   = wave >> 2;      // 0..1  (M half)
  const int wn   = wave & 3;       // 0..3  (N quarter)

  const long rowA0 = (long)blockIdx.y * BM;
  const long rowB0 = (long)blockIdx.x * BN;

  // staging lane geometry: one GLOAD issue covers 64 rows x 64B (8 KB/block).
  // LDS linear: row = q*64 + wave*8 + (lane>>3), phys slot = lane&7.
  // source col chunk = inverse swizzle = phys ^ (row&7).
  const int sg_col = (((lane & 7) ^ ((lane >> 3) & 7)) << 3);
  const int s_rlo  = wave * 8 + (lane >> 3);

  // fragment-read lane offsets (bytes within a half): row = <frag>*16 + (lane&15),
  // phys = (kk*4 + lane>>4) ^ (row&7) = (kk*4 + lane>>4) ^ (lane&7).
  const int offk0 = (lane & 15) * 128 + ((((lane >> 4)) ^ (lane & 7)) << 4);
  const int offk1 = (lane & 15) * 128 + (((4 + (lane >> 4)) ^ (lane & 7)) << 4);

  auto stage = [&](char* bufb, int half, int tt) {
    const long grow = (half < 2 ? rowA0 + (long)half * 128 : rowB0 + (long)(half - 2) * 128) + s_rlo;
    const short* g = (half < 2 ? Abf : Bbf) + grow * (long)K_DIM + (long)tt * BK + sg_col;
    char* l = bufb + half * 16384 + wave * 1024;
    GLOAD_LDS16(g, l);                       /* rows q=0: 0-63 of half */
    GLOAD_LDS16(g + 64 * (long)K_DIM, l + 8192); /* rows q=1: 64-127 */
  };

  f32x4 acc[8][4];
#pragma unroll
  for (int i = 0; i < 8; ++i)
#pragma unroll
    for (int j = 0; j < 4; ++j) acc[i][j] = (f32x4)0.0f;

  // ---- prologue: tile 0 fully, A0+B0 of tile 1 ----
  stage(ldsb, 0, 0);
  stage(ldsb, 1, 0);
  stage(ldsb, 2, 0);
  stage(ldsb, 3, 0);
  stage(ldsb + 65536, 0, 1);
  stage(ldsb + 65536, 2, 1);
  asm volatile("s_waitcnt vmcnt(4)" ::: "memory");  // tile 0 resident
  __builtin_amdgcn_s_barrier();

  bf16x8 af[4][2], bfr[4][2];

  for (int t = 0; t < NKT; ++t) {
    const int c = t & 1;
    const char* ldsA = ldsb + c * 65536 + wm * 16384;
    const char* ldsB = ldsb + c * 65536 + 32768 + (wn >> 1) * 16384 + (wn & 1) * 8192;
    char* bnx  = ldsb + (c ^ 1) * 65536;  // buffer of tile t+1
    char* bnx2 = ldsb + c * 65536;        // buffer of tile t+2

    // ---------------- phase 0: A m0-3, B n0-1; stage A1(t+1) ----------------
#pragma unroll
    for (int m = 0; m < 4; ++m) {
      af[m][0] = *(const bf16x8*)(ldsA + m * 2048 + offk0);
      af[m][1] = *(const bf16x8*)(ldsA + m * 2048 + offk1);
    }
#pragma unroll
    for (int n = 0; n < 2; ++n) {
      bfr[n][0] = *(const bf16x8*)(ldsB + n * 2048 + offk0);
      bfr[n][1] = *(const bf16x8*)(ldsB + n * 2048 + offk1);
    }
    if (t + 1 < NKT) stage(bnx, 1, t + 1);
    asm volatile("s_waitcnt lgkmcnt(8)" ::: "memory");
    __builtin_amdgcn_s_barrier();
    asm volatile("s_waitcnt lgkmcnt(0)" ::: "memory");
    __builtin_amdgcn_sched_barrier(0);
    __builtin_amdgcn_s_setprio(1);
#pragma unroll
    for (int kk = 0; kk < 2; ++kk)
#pragma unroll
      for (int m = 0; m < 4; ++m)
#pragma unroll
        for (int n = 0; n < 2; ++n)
          acc[m][n] = __builtin_amdgcn_mfma_f32_16x16x32_bf16(af[m][kk], bfr[n][kk], acc[m][n], 0, 0, 0);
    __builtin_amdgcn_s_setprio(0);
    __builtin_amdgcn_s_barrier();

    // ---------------- phase 1: B n2-3; stage B1(t+1) ----------------
#pragma unroll
    for (int n = 2; n < 4; ++n) {
      bfr[n][0] = *(const bf16x8*)(ldsB + n * 2048 + offk0);
      bfr[n][1] = *(const bf16x8*)(ldsB + n * 2048 + offk1);
    }
    if (t + 1 < NKT) stage(bnx, 3, t + 1);
    __builtin_amdgcn_s_barrier();
    asm volatile("s_waitcnt lgkmcnt(0)" ::: "memory");
    __builtin_amdgcn_sched_barrier(0);
    __builtin_amdgcn_s_setprio(1);
#pragma unroll
    for (int kk = 0; kk < 2; ++kk)
#pragma unroll
      for (int m = 0; m < 4; ++m)
#pragma unroll
        for (int n = 2; n < 4; ++n)
          acc[m][n] = __builtin_amdgcn_mfma_f32_16x16x32_bf16(af[m][kk], bfr[n][kk], acc[m][n], 0, 0, 0);
    __builtin_amdgcn_s_setprio(0);
    __builtin_amdgcn_s_barrier();

    // ---------------- phase 2: A m4-7; no stage ----------------
#pragma unroll
    for (int m = 0; m < 4; ++m) {
      af[m][0] = *(const bf16x8*)(ldsA + (4 + m) * 2048 + offk0);
      af[m][1] = *(const bf16x8*)(ldsA + (4 + m) * 2048 + offk1);
    }
    __builtin_amdgcn_s_barrier();
    asm volatile("s_waitcnt lgkmcnt(0)" ::: "memory");
    __builtin_amdgcn_sched_barrier(0);
    __builtin_amdgcn_s_setprio(1);
#pragma unroll
    for (int kk = 0; kk < 2; ++kk)
#pragma unroll
      for (int m = 0; m < 4; ++m)
#pragma unroll
        for (int n = 0; n < 2; ++n)
          acc[4 + m][n] = __builtin_amdgcn_mfma_f32_16x16x32_bf16(af[m][kk], bfr[n][kk], acc[4 + m][n], 0, 0, 0);
    __builtin_amdgcn_s_setprio(0);
    __builtin_amdgcn_s_barrier();

    // ------- phase 3: no ds_read; stage A0,B0(t+2); counted vmcnt -------
    if (t + 2 < NKT) {
      stage(bnx2, 0, t + 2);
      stage(bnx2, 2, t + 2);
    }
    __builtin_amdgcn_s_setprio(1);
#pragma unroll
    for (int kk = 0; kk < 2; ++kk)
#pragma unroll
      for (int m = 0; m < 4; ++m)
#pragma unroll
        for (int n = 2; n < 4; ++n)
          acc[4 + m][n] = __builtin_amdgcn_mfma_f32_16x16x32_bf16(af[m][kk], bfr[n][kk], acc[4 + m][n], 0, 0, 0);
    __builtin_amdgcn_s_setprio(0);
    if (t + 2 < NKT)
      asm volatile("s_waitcnt vmcnt(4)" ::: "memory");  // tile t+1 resident; t+2's A0,B0 in flight
    else
      asm volatile("s_waitcnt vmcnt(0)" ::: "memory");  // drain for final tiles
    __builtin_amdgcn_s_barrier();
  }

  // ---- epilogue: bias + relu, fp32 stores ----
  const int c0 = lane & 15;
  const int r0 = (lane >> 4) * 4;
#pragma unroll
  for (int j = 0; j < 4; ++j) {
    const long gc = rowB0 + wn * 64 + j * 16 + c0;
    const float bv = bias[gc];
#pragma unroll
    for (int i = 0; i < 8; ++i) {
      const long gr0 = rowA0 + wm * 128 + i * 16 + r0;
#pragma unroll
      for (int r = 0; r < 4; ++r) {
        float v = acc[i][j][r] + bv;
        Y[(gr0 + r) * (long)N_DIM + gc] = fmaxf(v, 0.0f);
      }
    }
  }
}

// ---------------------------------------------------------------------------
// Fallback (only if ws too small): fp32 reg-staged 128^2 kernel.
// ---------------------------------------------------------------------------
#define FBM 128
#define FBK 32
#define FLDSS 40
__global__ __launch_bounds__(256) void fallback_gemm(
    const float* __restrict__ X, const float* __restrict__ W,
    const float* __restrict__ bias, float* __restrict__ Y) {
  __shared__ short As[FBM * FLDSS];
  __shared__ short Bs[FBM * FLDSS];
  const int tid = threadIdx.x, lane = tid & 63, wave = tid >> 6;
  const int wm = (wave >> 1) * 64, wn = (wave & 1) * 64;
  const long rowA0 = (long)blockIdx.y * FBM, rowB0 = (long)blockIdx.x * FBM;
  const int srow = tid >> 3, scol = (tid & 7) * 4;
  const float* Aptr = X + (rowA0 + srow) * (long)K_DIM + scol;
  const float* Bptr = W + (rowB0 + srow) * (long)K_DIM + scol;
  f32x4 ra[4], rb[4];
#pragma unroll
  for (int i = 0; i < 4; ++i) {
    ra[i] = *(const f32x4*)(Aptr + (long)i * 32 * K_DIM);
    rb[i] = *(const f32x4*)(Bptr + (long)i * 32 * K_DIM);
  }
  f32x4 acc[4][4];
#pragma unroll
  for (int i = 0; i < 4; ++i)
#pragma unroll
    for (int j = 0; j < 4; ++j) acc[i][j] = (f32x4)0.0f;
  for (int kt = 0; kt < K_DIM / FBK; ++kt) {
    __syncthreads();
#pragma unroll
    for (int i = 0; i < 4; ++i) {
      bf16x4v pa, pb;
#pragma unroll
      for (int j = 0; j < 4; ++j) {
        pa[j] = (short)__bfloat16_as_ushort(__float2bfloat16(ra[i][j]));
        pb[j] = (short)__bfloat16_as_ushort(__float2bfloat16(rb[i][j]));
      }
      *(bf16x4v*)&As[(i * 32 + srow) * FLDSS + scol] = pa;
      *(bf16x4v*)&Bs[(i * 32 + srow) * FLDSS + scol] = pb;
    }
    if (kt + 1 < K_DIM / FBK) {
      const float* An = Aptr + (kt + 1) * FBK;
      const float* Bn = Bptr + (kt + 1) * FBK;
#pragma unroll
      for (int i = 0; i < 4; ++i) {
        ra[i] = *(const f32x4*)(An + (long)i * 32 * K_DIM);
        rb[i] = *(const f32x4*)(Bn + (long)i * 32 * K_DIM);
      }
    }
    __syncthreads();
    bf16x8 af[4], bfr[4];
#pragma unroll
    for (int i = 0; i < 4; ++i) {
      af[i]  = *(const bf16x8*)&As[(wm + i * 16 + (lane & 15)) * FLDSS + (lane >> 4) * 8];
      bfr[i] = *(const bf16x8*)&Bs[(wn + i * 16 + (lane & 15)) * FLDSS + (lane >> 4) * 8];
    }
#pragma unroll
    for (int i = 0; i < 4; ++i)
#pragma unroll
      for (int j = 0; j < 4; ++j)
        acc[i][j] = __builtin_amdgcn_mfma_f32_16x16x32_bf16(af[i], bfr[j], acc[i][j], 0, 0, 0);
  }
  const int r0 = (lane >> 4) * 4, c0 = lane & 15;
#pragma unroll
  for (int j = 0; j < 4; ++j) {
    const long gc = rowB0 + wn + j * 16 + c0;
    const float bv = bias[gc];
#pragma unroll
    for (int i = 0; i < 4; ++i) {
      const long gr0 = rowA0 + wm + i * 16 + r0;
#pragma unroll
      for (int r = 0; r < 4; ++r) {
        float v = acc[i][j][r] + bv;
        Y[(gr0 + r) * (long)N_DIM + gc] = fmaxf(v, 0.0f);
      }
    }
  }
}

extern "C" void kernel_launch(void* const* d_in, const int* in_sizes, int n_in,
                              void* d_out, int out_size, void* d_ws, size_t ws_size,
                              hipStream_t stream) {
  const float* x = (const float*)d_in[0];
  const float* w = (const float*)d_in[1];
  const float* b = (const float*)d_in[2];
  float* y = (float*)d_out;

  const size_t need = (size_t)(NX + NW) * sizeof(short);
  if (ws_size >= need) {
    short* ws = (short*)d_ws;
    convert_bf16<<<2048, 256, 0, stream>>>(x, w, ws);
    dim3 grid(N_DIM / BN, M_DIM / BM);
    gemm256_bf16<<<grid, dim3(THREADS), 0, stream>>>(ws, ws + NX, b, y);
  } else {
    dim3 grid(N_DIM / FBM, M_DIM / FBM);
    fallback_gemm<<<grid, dim3(256), 0, stream>>>(x, w, b, y);
  }
}